// Round 3
// baseline (224.556 us; speedup 1.0000x reference)
//
#include <hip/hip_runtime.h>

namespace {

typedef __attribute__((ext_vector_type(2))) float f32x2;
typedef __attribute__((ext_vector_type(4))) float f32x4;

constexpr int Hd = 512, Wd = 512;
constexpr int TW = 256;           // cols per block
constexpr int TH = 32;            // rows per block
constexpr int G  = 4;             // rows per group (barrier period)
constexpr int NG = TH / G;        // 8 groups
constexpr int RAD = 5, WS = 11;
constexpr int NIN = G + WS - 1;   // 14 input rows per group
constexpr int SC  = TW + 2*RAD;   // 266 staged cols
constexpr int HSTR = 268;         // padded stride (keeps rows 16B-aligned)
constexpr float C1c = 1e-4f;      // (0.01*1.0)^2
constexpr float C2c = 9e-4f;      // (0.03*1.0)^2

__device__ __forceinline__ float rcp_fast(float x) { return __builtin_amdgcn_rcpf(x); }

// 21.4 KB LDS -> 7 blocks/CU; 256 thr -> 4 waves; grid 1536 = 6 blocks/CU resident
__global__ __launch_bounds__(256, 8) void ssim_map_kernel(
    const float* __restrict__ img1,
    const float* __restrict__ img2,
    const float* __restrict__ kern,
    float* __restrict__ out)
{
    __shared__ __align__(16) f32x2 hb01[G * HSTR];  // {V1, V2}   8576 B
    __shared__ __align__(16) f32x2 hb23[G * HSTR];  // {E11, E22} 8576 B
    __shared__ __align__(16) float hb4 [G * HSTR];  // V12        4288 B

    const int tid  = threadIdx.x;
    const int cb   = blockIdx.x;               // col band (0,1)
    const int row0 = blockIdx.y * TH;
    const long pbase = (long)blockIdx.z * (long)(Hd * Wd);
    const int col0 = cb * TW;

    // ---- recover 1D gaussian: g[j] = k[5][j] / sum(k[5][:]) (uniform) ----
    float g[WS];
    {
        float s = 0.f;
#pragma unroll
        for (int j = 0; j < WS; ++j) s += kern[RAD * WS + j];
        const float inv = 1.0f / s;
#pragma unroll
        for (int j = 0; j < WS; ++j) g[j] = kern[RAD * WS + j] * inv;
    }

    const int hr = tid >> 6;     // horizontal phase: row in group (0..3)
    const int hu = tid & 63;     // horizontal phase: out cols 4hu..4hu+3

    for (int grp = 0; grp < NG; ++grp) {
        __syncthreads();   // previous group's horizontal reads must finish

        // ============ vertical pass (global -> regs -> LDS) ============
        const int ibase = row0 + grp * G - RAD;    // first input row (uniform)
        for (int s = tid; s < SC; s += 256) {      // 10 threads (wave 0) do 2 cols
            int gc = col0 - RAD + s;               // column reflect
            gc = (gc < 0) ? -gc : gc;
            gc = (gc >= Wd) ? (2 * Wd - 2 - gc) : gc;

            f32x2 a01[G], a23[G]; float a4[G];
#pragma unroll
            for (int r = 0; r < G; ++r) {
                a01[r].x = 0.f; a01[r].y = 0.f;
                a23[r].x = 0.f; a23[r].y = 0.f;
                a4[r] = 0.f;
            }
#pragma unroll
            for (int j = 0; j < NIN; ++j) {
                int gr = ibase + j;                // row reflect (uniform -> SALU)
                gr = (gr < 0) ? -gr : gr;
                gr = (gr >= Hd) ? (2 * Hd - 2 - gr) : gr;
                const long off = pbase + (long)gr * Wd + gc;
                const float a = img1[off];
                const float b = img2[off];
                f32x2 ab; ab.x = a; ab.y = b;
                const f32x2 pp = ab * ab;          // v_pk_mul_f32 {a*a, b*b}
                const float p12 = a * b;
#pragma unroll
                for (int r = 0; r < G; ++r) {
                    const int k = j - r;           // compile-time tap index
                    if (k >= 0 && k < WS) {
                        f32x2 w2; w2.x = g[k]; w2.y = g[k];
                        a01[r] = __builtin_elementwise_fma(w2, ab, a01[r]);
                        a23[r] = __builtin_elementwise_fma(w2, pp, a23[r]);
                        a4[r]  = fmaf(g[k], p12, a4[r]);
                    }
                }
            }
#pragma unroll
            for (int r = 0; r < G; ++r) {
                hb01[r * HSTR + s] = a01[r];       // ds_write_b64, stride-1
                hb23[r * HSTR + s] = a23[r];
                hb4 [r * HSTR + s] = a4[r];
            }
        }

        __syncthreads();

        // ============ horizontal pass + epilogue (4 cols x 1 row / thread) ====
        // needs staged idx [4hu .. 4hu+13]  (= cols 4hu-5 .. 4hu+8)
        f32x2 h01[4], h23[4];
        float h4[4];
        {
            const f32x4* p4 = (const f32x4*)&hb01[hr * HSTR + 4 * hu];
            f32x2 f[14];
#pragma unroll
            for (int i = 0; i < 7; ++i) {          // 7 aligned b128
                const f32x4 t = p4[i];
                f[2*i]   = t.lo;
                f[2*i+1] = t.hi;
            }
#pragma unroll
            for (int j = 0; j < 4; ++j) { h01[j].x = 0.f; h01[j].y = 0.f; }
#pragma unroll
            for (int k = 0; k < WS; ++k) {
                f32x2 w2; w2.x = g[k]; w2.y = g[k];
#pragma unroll
                for (int j = 0; j < 4; ++j)
                    h01[j] = __builtin_elementwise_fma(w2, f[k + j], h01[j]);
            }
        }
        {
            const f32x4* p4 = (const f32x4*)&hb23[hr * HSTR + 4 * hu];
            f32x2 f[14];
#pragma unroll
            for (int i = 0; i < 7; ++i) {
                const f32x4 t = p4[i];
                f[2*i]   = t.lo;
                f[2*i+1] = t.hi;
            }
#pragma unroll
            for (int j = 0; j < 4; ++j) { h23[j].x = 0.f; h23[j].y = 0.f; }
#pragma unroll
            for (int k = 0; k < WS; ++k) {
                f32x2 w2; w2.x = g[k]; w2.y = g[k];
#pragma unroll
                for (int j = 0; j < 4; ++j)
                    h23[j] = __builtin_elementwise_fma(w2, f[k + j], h23[j]);
            }
        }
        {
            const float* base = &hb4[hr * HSTR + 4 * hu];
            const f32x4 v0 = *(const f32x4*)(base);
            const f32x4 v1 = *(const f32x4*)(base + 4);
            const f32x4 v2 = *(const f32x4*)(base + 8);
            const f32x2 v3 = *(const f32x2*)(base + 12);
            const float f[14] = { v0.x, v0.y, v0.z, v0.w,
                                  v1.x, v1.y, v1.z, v1.w,
                                  v2.x, v2.y, v2.z, v2.w,
                                  v3.x, v3.y };
#pragma unroll
            for (int j = 0; j < 4; ++j) h4[j] = 0.f;
#pragma unroll
            for (int k = 0; k < WS; ++k) {
                const float w = g[k];
#pragma unroll
                for (int j = 0; j < 4; ++j)
                    h4[j] = fmaf(w, f[k + j], h4[j]);
            }
        }

        f32x4 res;
        float rr[4];
#pragma unroll
        for (int j = 0; j < 4; ++j) {
            const f32x2 mm  = h01[j];              // {m1, m2}
            const f32x2 msq = mm * mm;             // {m1^2, m2^2}
            const f32x2 sg  = h23[j] - msq;        // {sg1, sg2}
            const float m12  = mm.x * mm.y;
            const float sg12 = h4[j] - m12;
            const float num = (2.f * m12 + C1c) * (2.f * sg12 + C2c);
            const float den = (msq.x + msq.y + C1c) * (sg.x + sg.y + C2c);
            rr[j] = num * rcp_fast(den);
        }
        res.x = rr[0]; res.y = rr[1]; res.z = rr[2]; res.w = rr[3];
        f32x4* po = (f32x4*)&out[pbase + (long)(row0 + grp * G + hr) * Wd + col0 + 4 * hu];
        *po = res;
    }
}

} // namespace

extern "C" void kernel_launch(void* const* d_in, const int* in_sizes, int n_in,
                              void* d_out, int out_size, void* d_ws, size_t ws_size,
                              hipStream_t stream) {
    const float* img1 = (const float*)d_in[0];
    const float* img2 = (const float*)d_in[1];
    const float* kern = (const float*)d_in[2];
    float* outp = (float*)d_out;
    dim3 grid(Wd / TW, Hd / TH, 48);   // 2 x 16 x 48 = 1536 blocks = 6/CU
    ssim_map_kernel<<<grid, dim3(256), 0, stream>>>(img1, img2, kern, outp);
}

// Round 4
// 172.568 us; speedup vs baseline: 1.3013x; 1.3013x over previous
//
#include <hip/hip_runtime.h>

namespace {

typedef __attribute__((ext_vector_type(2))) float f32x2;
typedef __attribute__((ext_vector_type(4))) float f32x4;

constexpr int Hd = 512, Wd = 512;
constexpr int TH = 32;             // output rows per block (band)
constexpr int R  = 4;              // rows per LDS phase (barrier period)
constexpr int NCH = TH / R;        // 8 chunks
constexpr int RAD = 5, WS = 11;
constexpr int HSTR = 524;          // 5+512+5=522 used, padded (16B-aligned rows)
constexpr float C1c = 1e-4f;       // (0.01*1.0)^2
constexpr float C2c = 9e-4f;       // (0.03*1.0)^2

__device__ __forceinline__ float rcp_fast(float x) { return __builtin_amdgcn_rcpf(x); }
__device__ __forceinline__ float sgpr_f(float x) {
    return __int_as_float(__builtin_amdgcn_readfirstlane(__float_as_int(x)));
}

// LDS 41.9 KB; VGPR capped 128 -> 2 blocks (16 waves) per CU
__global__ __launch_bounds__(512, 4) void ssim_map_kernel(
    const float* __restrict__ img1,
    const float* __restrict__ img2,
    const float* __restrict__ kern,
    float* __restrict__ out)
{
    __shared__ __align__(16) f32x2 hb01[R * HSTR];  // {V1,V2}
    __shared__ __align__(16) f32x2 hb23[R * HSTR];  // {E11,E22}
    __shared__ __align__(16) float hb4 [R * HSTR];  // V12

    const int tid  = threadIdx.x;
    const int c    = tid;                       // owned column
    const int row0 = blockIdx.x * TH;
    const long pbase = (long)blockIdx.y * (long)(Hd * Wd);

    // ---- 1D gaussian (uniform, forced to SGPRs): g[j] = k[5][j]/sum ----
    float g[WS];
    {
        float s = 0.f;
#pragma unroll
        for (int j = 0; j < WS; ++j) s += kern[RAD * WS + j];
        const float inv = 1.0f / s;
#pragma unroll
        for (int j = 0; j < WS; ++j) g[j] = sgpr_f(kern[RAD * WS + j] * inv);
    }

    // ---- ring accumulators: slot(out_row o) = o % 11 ----
    f32x2 aV[WS], aE[WS];
    float aP[WS];
#pragma unroll
    for (int i = 0; i < WS; ++i) {
        aV[i].x = 0.f; aV[i].y = 0.f;
        aE[i].x = 0.f; aE[i].y = 0.f;
        aP[i] = 0.f;
    }

    // ---- fill: input idx j=0..9 (rows row0-5+j), taps k<=j only ----
#pragma unroll
    for (int j = 0; j < 2 * RAD; ++j) {
        int gr = row0 - RAD + j;                // uniform reflect -> SALU
        gr = (gr < 0) ? -gr : gr;
        gr = (gr >= Hd) ? (2 * Hd - 2 - gr) : gr;
        const long off = pbase + (long)gr * Wd + c;
        const float a = img1[off];
        const float b = img2[off];
        f32x2 ab; ab.x = a; ab.y = b;
        const f32x2 pp = ab * ab;
        const float p12 = a * b;
#pragma unroll
        for (int k = 0; k < WS; ++k) {
            if (k <= j) {
                const int slot = (j - k) % WS;  // static after unroll
                f32x2 w2; w2.x = g[k]; w2.y = g[k];
                aV[slot] = __builtin_elementwise_fma(w2, ab, aV[slot]);
                aE[slot] = __builtin_elementwise_fma(w2, pp, aE[slot]);
                aP[slot] = fmaf(g[k], p12, aP[slot]);
            }
        }
    }

    const int hr = tid >> 7;      // horizontal: row in chunk (0..3)
    const int hu = tid & 127;     // horizontal: out cols 4hu..4hu+3

#pragma unroll
    for (int ch = 0; ch < NCH; ++ch) {
        __syncthreads();          // prev chunk's readers done before overwrite

        // ---- steady vertical: 1 input row -> 1 completed output row ----
#pragma unroll
        for (int i = 0; i < R; ++i) {
            const int o = ch * R + i;           // out row in band
            const int j = o + 2 * RAD;          // input idx
            int gr = row0 - RAD + j;            // = row0 + 5 + o, reflect
            gr = (gr < 0) ? -gr : gr;
            gr = (gr >= Hd) ? (2 * Hd - 2 - gr) : gr;
            const long off = pbase + (long)gr * Wd + c;
            const float a = img1[off];
            const float b = img2[off];
            f32x2 ab; ab.x = a; ab.y = b;
            const f32x2 pp = ab * ab;
            const float p12 = a * b;
#pragma unroll
            for (int k = 0; k < WS; ++k) {
                const int slot = (j - k) % WS;  // static after unroll
                f32x2 w2; w2.x = g[k]; w2.y = g[k];
                aV[slot] = __builtin_elementwise_fma(w2, ab, aV[slot]);
                aE[slot] = __builtin_elementwise_fma(w2, pp, aE[slot]);
                aP[slot] = fmaf(g[k], p12, aP[slot]);
            }
            // emit completed out row o (slot o%11) to LDS row i
            const int es = o % WS;
            hb01[i * HSTR + RAD + c] = aV[es];
            hb23[i * HSTR + RAD + c] = aE[es];
            hb4 [i * HSTR + RAD + c] = aP[es];
            if (c >= 1 && c <= RAD) {                       // left reflect halo
                hb01[i * HSTR + RAD - c] = aV[es];
                hb23[i * HSTR + RAD - c] = aE[es];
                hb4 [i * HSTR + RAD - c] = aP[es];
            } else if (c >= Wd - 1 - RAD && c <= Wd - 2) {  // right reflect halo
                hb01[i * HSTR + RAD + 1022 - c] = aV[es];
                hb23[i * HSTR + RAD + 1022 - c] = aE[es];
                hb4 [i * HSTR + RAD + 1022 - c] = aP[es];
            }
            // zero slot for out row o+11
            aV[es].x = 0.f; aV[es].y = 0.f;
            aE[es].x = 0.f; aE[es].y = 0.f;
            aP[es] = 0.f;
        }

        __syncthreads();

        // ---- horizontal + epilogue: 4 cols x 1 row per thread ----
        f32x2 h01[4], h23[4];
        float h4[4];
        {
            const f32x4* p4 = (const f32x4*)&hb01[hr * HSTR + 4 * hu];
            f32x2 f[14];
#pragma unroll
            for (int i = 0; i < 7; ++i) {
                const f32x4 t = p4[i];
                f[2*i] = t.lo; f[2*i+1] = t.hi;
            }
#pragma unroll
            for (int j = 0; j < 4; ++j) { h01[j].x = 0.f; h01[j].y = 0.f; }
#pragma unroll
            for (int k = 0; k < WS; ++k) {
                f32x2 w2; w2.x = g[k]; w2.y = g[k];
#pragma unroll
                for (int j = 0; j < 4; ++j)
                    h01[j] = __builtin_elementwise_fma(w2, f[k + j], h01[j]);
            }
        }
        {
            const f32x4* p4 = (const f32x4*)&hb23[hr * HSTR + 4 * hu];
            f32x2 f[14];
#pragma unroll
            for (int i = 0; i < 7; ++i) {
                const f32x4 t = p4[i];
                f[2*i] = t.lo; f[2*i+1] = t.hi;
            }
#pragma unroll
            for (int j = 0; j < 4; ++j) { h23[j].x = 0.f; h23[j].y = 0.f; }
#pragma unroll
            for (int k = 0; k < WS; ++k) {
                f32x2 w2; w2.x = g[k]; w2.y = g[k];
#pragma unroll
                for (int j = 0; j < 4; ++j)
                    h23[j] = __builtin_elementwise_fma(w2, f[k + j], h23[j]);
            }
        }
        {
            const float* base = &hb4[hr * HSTR + 4 * hu];
            const f32x4 v0 = *(const f32x4*)(base);
            const f32x4 v1 = *(const f32x4*)(base + 4);
            const f32x4 v2 = *(const f32x4*)(base + 8);
            const f32x2 v3 = *(const f32x2*)(base + 12);
            const float f[14] = { v0.x, v0.y, v0.z, v0.w,
                                  v1.x, v1.y, v1.z, v1.w,
                                  v2.x, v2.y, v2.z, v2.w,
                                  v3.x, v3.y };
#pragma unroll
            for (int j = 0; j < 4; ++j) h4[j] = 0.f;
#pragma unroll
            for (int k = 0; k < WS; ++k) {
#pragma unroll
                for (int j = 0; j < 4; ++j)
                    h4[j] = fmaf(g[k], f[k + j], h4[j]);
            }
        }

        float rr[4];
#pragma unroll
        for (int j = 0; j < 4; ++j) {
            const f32x2 mm  = h01[j];            // {m1, m2}
            const f32x2 msq = mm * mm;
            const f32x2 sg  = h23[j] - msq;      // {sg1, sg2}
            const float m12  = mm.x * mm.y;
            const float sg12 = h4[j] - m12;
            const float num = (2.f * m12 + C1c) * (2.f * sg12 + C2c);
            const float den = (msq.x + msq.y + C1c) * (sg.x + sg.y + C2c);
            rr[j] = num * rcp_fast(den);
        }
        f32x4 res; res.x = rr[0]; res.y = rr[1]; res.z = rr[2]; res.w = rr[3];
        f32x4* po = (f32x4*)&out[pbase + (long)(row0 + ch * R + hr) * Wd + 4 * hu];
        *po = res;
    }
}

} // namespace

extern "C" void kernel_launch(void* const* d_in, const int* in_sizes, int n_in,
                              void* d_out, int out_size, void* d_ws, size_t ws_size,
                              hipStream_t stream) {
    const float* img1 = (const float*)d_in[0];
    const float* img2 = (const float*)d_in[1];
    const float* kern = (const float*)d_in[2];
    float* outp = (float*)d_out;
    dim3 grid(Hd / TH, 48);   // 16 bands x 48 planes = 768 blocks
    ssim_map_kernel<<<grid, dim3(512), 0, stream>>>(img1, img2, kern, outp);
}

// Round 5
// 161.885 us; speedup vs baseline: 1.3871x; 1.0660x over previous
//
#include <hip/hip_runtime.h>

namespace {

typedef __attribute__((ext_vector_type(2))) float f32x2;
typedef __attribute__((ext_vector_type(4))) float f32x4;

constexpr int Hd = 512, Wd = 512;
constexpr int TH = 32;             // output rows per block (band)
constexpr int R  = 4;              // rows per LDS phase (barrier period)
constexpr int NCH = TH / R;        // 8 chunks
constexpr int RAD = 5, WS = 11;
constexpr int HSTR = 524;          // 5+512+5=522 used, padded
constexpr float C1c = 1e-4f;       // (0.01*1.0)^2
constexpr float C2c = 9e-4f;       // (0.03*1.0)^2

__device__ __forceinline__ float rcp_fast(float x) { return __builtin_amdgcn_rcpf(x); }
__device__ __forceinline__ float sgpr_f(float x) {
    return __int_as_float(__builtin_amdgcn_readfirstlane(__float_as_int(x)));
}

// LDS 33.5 KB (4 blocks/CU fit); VGPR capped at 85 by (512,6)
__global__ __launch_bounds__(512, 6) void ssim_map_kernel(
    const float* __restrict__ img1,
    const float* __restrict__ img2,
    const float* __restrict__ kern,
    float* __restrict__ out)
{
    // packed {mS, mD, QS, QD} per column, R rows
    __shared__ __align__(16) f32x4 hb[R * HSTR];   // 33.5 KB

    const int tid  = threadIdx.x;
    const int c    = tid;                       // owned column
    const int row0 = blockIdx.x * TH;
    const long pbase = (long)blockIdx.y * (long)(Hd * Wd);

    // ---- 1D gaussian (uniform -> SGPRs): g[j] = k[5][j]/sum ----
    float g[WS];
    {
        float s = 0.f;
#pragma unroll
        for (int j = 0; j < WS; ++j) s += kern[RAD * WS + j];
        const float inv = 1.0f / s;
#pragma unroll
        for (int j = 0; j < WS; ++j) g[j] = sgpr_f(kern[RAD * WS + j] * inv);
    }

    // ---- ring accumulators, slot(out_row o) = o % 11 ----
    f32x2 aM[WS];   // {conv(S), conv(D)}
    f32x2 aQ[WS];   // {conv(S^2), conv(D^2)}
#pragma unroll
    for (int i = 0; i < WS; ++i) {
        aM[i].x = 0.f; aM[i].y = 0.f;
        aQ[i].x = 0.f; aQ[i].y = 0.f;
    }

    // ---- fill: input idx j=0..9 (rows row0-5+j), taps k<=j ----
#pragma unroll
    for (int j = 0; j < 2 * RAD; ++j) {
        int gr = row0 - RAD + j;                // uniform reflect -> SALU
        gr = (gr < 0) ? -gr : gr;
        gr = (gr >= Hd) ? (2 * Hd - 2 - gr) : gr;
        const long off = pbase + (long)gr * Wd + c;
        const float a = img1[off];
        const float b = img2[off];
        f32x2 sd; sd.x = a + b; sd.y = a - b;
        const f32x2 qq = sd * sd;               // v_pk_mul_f32
#pragma unroll
        for (int k = 0; k < WS; ++k) {
            if (k <= j) {
                const int slot = (j - k) % WS;  // static after unroll
                f32x2 w2; w2.x = g[k]; w2.y = g[k];
                aM[slot] = __builtin_elementwise_fma(w2, sd, aM[slot]);
                aQ[slot] = __builtin_elementwise_fma(w2, qq, aQ[slot]);
            }
        }
    }

    const int hr = tid >> 7;      // horizontal: row in chunk (0..3)
    const int hu = tid & 127;     // horizontal: out cols 4hu..4hu+3

#pragma unroll
    for (int ch = 0; ch < NCH; ++ch) {
        __syncthreads();          // prev chunk's readers done before overwrite

        // ---- vertical: 1 input row -> 1 completed output row ----
#pragma unroll
        for (int i = 0; i < R; ++i) {
            const int o = ch * R + i;           // out row in band
            const int j = o + 2 * RAD;          // input idx
            int gr = row0 - RAD + j;            // reflect (uniform)
            gr = (gr < 0) ? -gr : gr;
            gr = (gr >= Hd) ? (2 * Hd - 2 - gr) : gr;
            const long off = pbase + (long)gr * Wd + c;
            const float a = img1[off];
            const float b = img2[off];
            f32x2 sd; sd.x = a + b; sd.y = a - b;
            const f32x2 qq = sd * sd;
#pragma unroll
            for (int k = 0; k < WS; ++k) {
                const int slot = (j - k) % WS;  // static after unroll
                f32x2 w2; w2.x = g[k]; w2.y = g[k];
                aM[slot] = __builtin_elementwise_fma(w2, sd, aM[slot]);
                aQ[slot] = __builtin_elementwise_fma(w2, qq, aQ[slot]);
            }
            // emit completed row o (slot o%11) -> LDS row i, one b128
            const int es = o % WS;
            f32x4 e;
            e.x = aM[es].x; e.y = aM[es].y;
            e.z = aQ[es].x; e.w = aQ[es].y;
            hb[i * HSTR + RAD + c] = e;
            if (c >= 1 && c <= RAD) {                       // left reflect halo
                hb[i * HSTR + RAD - c] = e;
            } else if (c >= Wd - 1 - RAD && c <= Wd - 2) {  // right reflect halo
                hb[i * HSTR + RAD + 1022 - c] = e;
            }
            aM[es].x = 0.f; aM[es].y = 0.f;     // free slot for row o+11
            aQ[es].x = 0.f; aQ[es].y = 0.f;
        }

        __syncthreads();

        // ---- horizontal + epilogue: 4 cols x 1 row per thread ----
        // streams one f32x4 at a time to keep register pressure low
        f32x2 hm[4], hq[4];
#pragma unroll
        for (int j = 0; j < 4; ++j) {
            hm[j].x = 0.f; hm[j].y = 0.f;
            hq[j].x = 0.f; hq[j].y = 0.f;
        }
        const f32x4* base = &hb[hr * HSTR + 4 * hu];
#pragma unroll
        for (int t = 0; t < 14; ++t) {          // staged idx 4hu+t (col 4hu+t-5)
            const f32x4 ft = base[t];           // ds_read_b128
            f32x2 fm; fm.x = ft.x; fm.y = ft.y;
            f32x2 fq; fq.x = ft.z; fq.y = ft.w;
#pragma unroll
            for (int j = 0; j < 4; ++j) {
                const int k = t - j;            // tap index, compile-time
                if (k >= 0 && k < WS) {
                    f32x2 w2; w2.x = g[k]; w2.y = g[k];
                    hm[j] = __builtin_elementwise_fma(w2, fm, hm[j]);
                    hq[j] = __builtin_elementwise_fma(w2, fq, hq[j]);
                }
            }
        }

        float rr[4];
#pragma unroll
        for (int j = 0; j < 4; ++j) {
            const f32x2 m = hm[j];              // {mS, mD}
            const f32x2 q = hq[j];              // {QS, QD}
            const f32x2 msq = m * m;            // {mS^2, mD^2}
            const float t1 = msq.x - msq.y;     // 4*mu1mu2
            const float t2 = msq.x + msq.y;     // 2*(mu1^2+mu2^2)
            const float q1 = q.x - q.y;         // 4*conv(ab)
            const float q2 = q.x + q.y;         // 2*conv(a^2+b^2)
            const float num = fmaf(0.5f, t1, C1c) * fmaf(0.5f, q1 - t1, C2c);
            const float den = fmaf(0.5f, t2, C1c) * fmaf(0.5f, q2 - t2, C2c);
            rr[j] = num * rcp_fast(den);
        }
        f32x4 res; res.x = rr[0]; res.y = rr[1]; res.z = rr[2]; res.w = rr[3];
        f32x4* po = (f32x4*)&out[pbase + (long)(row0 + ch * R + hr) * Wd + 4 * hu];
        *po = res;
    }
}

} // namespace

extern "C" void kernel_launch(void* const* d_in, const int* in_sizes, int n_in,
                              void* d_out, int out_size, void* d_ws, size_t ws_size,
                              hipStream_t stream) {
    const float* img1 = (const float*)d_in[0];
    const float* img2 = (const float*)d_in[1];
    const float* kern = (const float*)d_in[2];
    float* outp = (float*)d_out;
    dim3 grid(Hd / TH, 48);   // 16 bands x 48 planes = 768 blocks = 3/CU
    ssim_map_kernel<<<grid, dim3(512), 0, stream>>>(img1, img2, kern, outp);
}